// Round 8
// baseline (431.929 us; speedup 1.0000x reference)
//
#include <hip/hip_runtime.h>
#include <hip/hip_bf16.h>

#define DIM  256
#define NSEQ 8192
#define BATCH 8
#define WIN  512

typedef __attribute__((ext_vector_type(8))) short short8;    // bf16x8 (4 VGPRs)
typedef __attribute__((ext_vector_type(4))) float floatx4;   // 16x16 MFMA acc
typedef __attribute__((ext_vector_type(16))) float f32x16;   // 32x32 MFMA acc

union PFU { int i[4]; short8 v; };

__device__ __forceinline__ int packbf(float a, float b) {
    __hip_bfloat162 h;
    h.x = __float2bfloat16(a);
    h.y = __float2bfloat16(b);
    int r;
    __builtin_memcpy(&r, &h, 4);
    return r;
}

// ---------------------------------------------------------------------------
// Kernel 1: Wq,Wk,Wv f32 -> packed bf16 wb[3][256*256] (verified R9 config)
// ---------------------------------------------------------------------------
__global__ __launch_bounds__(256) void k_wcast(const float* __restrict__ w0,
                                               const float* __restrict__ w1,
                                               const float* __restrict__ w2,
                                               __hip_bfloat16* __restrict__ wb) {
    int i = (blockIdx.x * 256 + threadIdx.x) * 4;
    const float* s = (i < 65536) ? (w0 + i) : ((i < 131072) ? (w1 + i - 65536) : (w2 + i - 131072));
    float4 v = *(const float4*)s;
    union { __hip_bfloat16 h[4]; ushort4 u; } cv;
    cv.h[0] = __float2bfloat16(v.x);
    cv.h[1] = __float2bfloat16(v.y);
    cv.h[2] = __float2bfloat16(v.z);
    cv.h[3] = __float2bfloat16(v.w);
    *(ushort4*)(wb + i) = cv.u;
}

// ---------------------------------------------------------------------------
// Kernel 2: FUSED transpose + 3-mode projection (verified R9 config).
// ---------------------------------------------------------------------------
__global__ __launch_bounds__(256, 3) void k_prep(const float* __restrict__ x,
                                                 const __hip_bfloat16* __restrict__ wb,
                                                 const float* __restrict__ bq,
                                                 const float* __restrict__ bk,
                                                 const float* __restrict__ bv,
                                                 __hip_bfloat16* __restrict__ qo,
                                                 __hip_bfloat16* __restrict__ ko,
                                                 __hip_bfloat16* __restrict__ vto) {
    __shared__ float ftile[64][68];
    __shared__ __align__(16) char As[32768];
    const int b   = blockIdx.y;
    const int n0  = blockIdx.x * 64;
    const int tid = threadIdx.x;
    const int wv  = tid >> 6;
    const int l   = tid & 63;
    const int lm  = l & 15;
    const int qd  = l >> 4;
    const int wn  = wv * 64;

    const float* xb = x + (size_t)b * DIM * NSEQ;

    const int dr = l >> 4, nseg = l & 15;
#pragma unroll
    for (int dsl = 0; dsl < 4; ++dsl) {
        const int d0 = dsl * 64;
#pragma unroll
        for (int i = 0; i < 4; ++i) {
            const int r = wv * 16 + i * 4 + dr;
            float4 v = *(const float4*)(xb + (size_t)(d0 + r) * NSEQ + n0 + nseg * 4);
            *(float4*)&ftile[r][nseg * 4] = v;
        }
        __syncthreads();
#pragma unroll
        for (int p = 0; p < 2; ++p) {
            const int ks = dsl * 2 + p;
            int4 pk;
            int* pki = (int*)&pk;
#pragma unroll
            for (int jj = 0; jj < 4; ++jj)
                pki[jj] = packbf(ftile[p * 32 + wv * 8 + jj * 2][l],
                                 ftile[p * 32 + wv * 8 + jj * 2 + 1][l]);
            *(int4*)(As + ks * 4096 + wv * 1024 + l * 16) = pk;
        }
        __syncthreads();
    }

#pragma unroll
    for (int mode = 0; mode < 3; ++mode) {
        const __hip_bfloat16* wp = wb + mode * 65536;
        floatx4 acc[4][4];
#pragma unroll
        for (int i = 0; i < 4; ++i)
#pragma unroll
            for (int j = 0; j < 4; ++j) acc[i][j] = (floatx4){0.f, 0.f, 0.f, 0.f};

#pragma unroll
        for (int ks = 0; ks < 8; ++ks) {
            short8 wf[4], af[4];
#pragma unroll
            for (int j = 0; j < 4; ++j)
                wf[j] = *(const short8*)(wp + (size_t)(wn + j * 16 + lm) * DIM + ks * 32 + qd * 8);
#pragma unroll
            for (int j = 0; j < 4; ++j)
                af[j] = *(const short8*)(As + ks * 4096 + qd * 1024 + (j * 16 + lm) * 16);
            if (mode < 2) {
#pragma unroll
                for (int mt = 0; mt < 4; ++mt)
#pragma unroll
                    for (int nt = 0; nt < 4; ++nt)
                        acc[mt][nt] = __builtin_amdgcn_mfma_f32_16x16x32_bf16(af[mt], wf[nt], acc[mt][nt], 0, 0, 0);
            } else {
#pragma unroll
                for (int jw = 0; jw < 4; ++jw)
#pragma unroll
                    for (int ja = 0; ja < 4; ++ja)
                        acc[jw][ja] = __builtin_amdgcn_mfma_f32_16x16x32_bf16(wf[jw], af[ja], acc[jw][ja], 0, 0, 0);
            }
        }

        if (mode < 2) {
            const float* bias = mode ? bk : bq;
            __hip_bfloat16* op = (mode ? ko : qo) + (size_t)b * NSEQ * DIM;
            float bc[4];
#pragma unroll
            for (int nt = 0; nt < 4; ++nt) bc[nt] = bias[wn + nt * 16 + lm];
#pragma unroll
            for (int mt = 0; mt < 4; ++mt)
#pragma unroll
                for (int nt = 0; nt < 4; ++nt)
#pragma unroll
                    for (int r = 0; r < 4; ++r)
                        op[(size_t)(n0 + mt * 16 + qd * 4 + r) * DIM + wn + nt * 16 + lm] =
                            __float2bfloat16(acc[mt][nt][r] + bc[nt]);
        } else {
            __hip_bfloat16* op = vto + (size_t)b * DIM * NSEQ;
#pragma unroll
            for (int jw = 0; jw < 4; ++jw)
#pragma unroll
                for (int r = 0; r < 4; ++r) {
                    const int d = wn + jw * 16 + qd * 4 + r;
                    const float bb = bv[d];
#pragma unroll
                    for (int ja = 0; ja < 4; ++ja)
                        op[(size_t)d * NSEQ + n0 + ja * 16 + lm] =
                            __float2bfloat16(acc[jw][ja][r] + bb);
                }
        }
    }
}

// ---------------------------------------------------------------------------
// Kernel 3 (R14): flash attention, 8 waves x 32 q, mfma_32x32x16 (m214-style).
// Why: R12's 16x16q waves re-read K+V per 16 q -> 512 KB LDS/chunk/CU (54%
// busy = the binding term). 32 q/wave halves fragment traffic per unit work
// (~3.8k cyc/chunk) and the swapped-QK 32x32 C-layout makes P lane-local:
// p[r] = P[q=lane&31][k=(r&3)+8*(r>>2)+4*(lane>>5)] (guide SecB verified).
// Softmax: 15 in-lane fmax + 1 shfl_xor(32); pf assembly: 4 bpermutes
// (lane^32 exchange) + selects, vs 8 bpermutes + 4 shfl before.
// LDS swizzles (reg-staged, both-sides):
//   K rows 512 B:  phys16Bslot = (d-slot) ^ key        (conflict-free)
//   V^T 8-row groups of 512 B: phys = ((j*8+d&7) ^ dg) (uniform banks)
// Regs ~250 @ __launch_bounds__(512,2) = 2 waves/SIMD; m214 showed this
// occupancy is fine when the serial softmax is short. T5+T13 retained.
// ---------------------------------------------------------------------------
__global__ __launch_bounds__(512, 2) void k_attn(const __hip_bfloat16* __restrict__ qm,
                                                 const __hip_bfloat16* __restrict__ km,
                                                 const __hip_bfloat16* __restrict__ vtm,
                                                 const float* __restrict__ x,
                                                 float* __restrict__ out) {
    __shared__ __align__(16) char kbuf[2][16384];
    __shared__ __align__(16) char vbuf[2][16384];

    const int w  = blockIdx.x, b = blockIdx.y, qt = blockIdx.z;
    const int tid = threadIdx.x;
    const int wv = tid >> 6;   // 0..7
    const int l  = tid & 63;
    const int q5 = l & 31;     // q within wave tile; also key row / d row in frags
    const int hi = l >> 5;

    const int qbw   = qt * 256 + wv * 32;   // wave q-base within window
    const int koff0 = w * WIN - WIN;        // global row of key_local 0

    // ---- Q fragments: B-operand Q[32 q][256 d], 16 d-slices ----
    short8 qfr[16];
    {
        const __hip_bfloat16* qrow =
            qm + ((size_t)b * NSEQ + (size_t)(w * WIN + qbw + q5)) * DIM;
#pragma unroll
        for (int s = 0; s < 16; ++s)
            qfr[s] = *(const short8*)(qrow + s * 16 + hi * 8);
    }

    const char* kbase = (const char*)(km + (size_t)b * NSEQ * DIM);
    const char* vbase = (const char*)(vtm + (size_t)b * DIM * NSEQ);

    const int c0  = (w == 0) ? 16 : 0;
    const int c1w = (575 + qbw) >> 5;            // per-wave chunk end (32 q rows)
    const int c1b = (799 + qt * 256) >> 5;       // block-level end (wave 7)

    // ---- staging: waves 0-3 stage K (8 keys each), 4-7 stage V (64 d each) ----
    const bool isK = wv < 4;
    const char* gp0;
    int lwo[4];
    size_t adv;
    if (isK) {
        const int key = wv * 8 + (l >> 3), seg = l & 7;
        gp0 = kbase + (size_t)(koff0 + c0 * 32 + key) * 512 + seg * 64;
        adv = (size_t)32 * 512;
#pragma unroll
        for (int j = 0; j < 4; ++j)
            lwo[j] = key * 512 + (((seg * 4 + j) ^ key) << 4);
    } else {
        const int dl = (wv - 4) * 64 + l, dg = dl >> 3, d7 = dl & 7;
        gp0 = vbase + (size_t)dl * (NSEQ * 2) + (size_t)(koff0 + c0 * 32) * 2;
        adv = 64;
#pragma unroll
        for (int j = 0; j < 4; ++j)
            lwo[j] = dg * 512 + (((j * 8 + d7) ^ dg) << 4);
    }

    f32x16 o[8];
#pragma unroll
    for (int t = 0; t < 8; ++t)
#pragma unroll
        for (int r = 0; r < 16; ++r) o[t][r] = 0.f;
    float mi = -INFINITY;
    float li = 0.f;
    const float sscale = 0.0625f * 1.4426950408889634f;  // D^-0.5 * log2(e)

    const int paddr = (l ^ 32) * 4;   // bpermute: pull from partner lane

    // ---- prologue: stage chunk c0 into buf[0] ----
    int4 rg[4];
#pragma unroll
    for (int j = 0; j < 4; ++j)
        rg[j] = *(const int4*)(gp0 + (size_t)j * 16);
    gp0 += adv;
    {
        char* d0 = (isK ? kbuf[0] : vbuf[0]);
#pragma unroll
        for (int j = 0; j < 4; ++j)
            *(int4*)(d0 + lwo[j]) = rg[j];
    }
    __syncthreads();

    int pb = 0;
    for (int c = c0; c < c1b; ++c) {
        const bool more = (c + 1 < c1b);
        if (more) {
#pragma unroll
            for (int j = 0; j < 4; ++j)
                rg[j] = *(const int4*)(gp0 + (size_t)j * 16);
            gp0 += adv;
        }
        if (c < c1w) {
            // ---- QK: S = K(32k x 256d) . Q^T -> lane: q=q5, 16 k-values ----
            const char* kb = kbuf[pb];
            f32x16 st;
#pragma unroll
            for (int r = 0; r < 16; ++r) st[r] = 0.f;
            __builtin_amdgcn_s_setprio(1);   // T5
#pragma unroll
            for (int s = 0; s < 16; ++s) {
                short8 kf = *(const short8*)(kb + q5 * 512 + ((((s * 2 + hi)) ^ q5) << 4));
                st = __builtin_amdgcn_mfma_f32_32x32x16_bf16(kf, qfr[s], st, 0, 0, 0);
            }
            __builtin_amdgcn_s_setprio(0);

            // ---- softmax: p[r] at k = (r&3)+8*(r>>2)+4*hi ----
            const int kl0 = c * 32;
            const int lim = 512 + qbw + q5;
            const bool needmask = (kl0 + 31) > lim;
            float p[16];
#pragma unroll
            for (int r = 0; r < 16; ++r) {
                float v = st[r] * sscale;
                if (needmask) {
                    int k = kl0 + (r & 3) + 8 * (r >> 2) + 4 * hi;
                    v = (k <= lim) ? v : -INFINITY;
                }
                p[r] = v;
            }
            float mx = p[0];
#pragma unroll
            for (int r = 1; r < 16; ++r) mx = fmaxf(mx, p[r]);
            mx = fmaxf(mx, __shfl_xor(mx, 32, 64));
            float mnew;                         // T13 defer-max
            if (__all(mx <= mi + 8.0f)) mnew = mi;
            else                        mnew = fmaxf(mi, mx);
            const float alpha = exp2f(mi - mnew);
            float ps = 0.f;
#pragma unroll
            for (int r = 0; r < 16; ++r) { p[r] = exp2f(p[r] - mnew); ps += p[r]; }
            ps += __shfl_xor(ps, 32, 64);
            li = li * alpha + ps;
            mi = mnew;
            if (!__all(alpha == 1.0f)) {
#pragma unroll
                for (int t = 0; t < 8; ++t)
#pragma unroll
                    for (int r = 0; r < 16; ++r) o[t][r] *= alpha;
            }

            // ---- pf assembly: 8 packs + 4 bpermutes (lane^32) + selects ----
            const int A0 = packbf(p[0], p[1]),  A1 = packbf(p[2], p[3]);
            const int B0 = packbf(p[4], p[5]),  B1 = packbf(p[6], p[7]);
            const int C0 = packbf(p[8], p[9]),  C1 = packbf(p[10], p[11]);
            const int D0 = packbf(p[12], p[13]), D1 = packbf(p[14], p[15]);
            const int Z0 = hi ? A0 : B0, Z1 = hi ? A1 : B1;
            const int Z2 = hi ? C0 : D0, Z3 = hi ? C1 : D1;
            const int P0 = __builtin_amdgcn_ds_bpermute(paddr, Z0);
            const int P1 = __builtin_amdgcn_ds_bpermute(paddr, Z1);
            const int P2 = __builtin_amdgcn_ds_bpermute(paddr, Z2);
            const int P3 = __builtin_amdgcn_ds_bpermute(paddr, Z3);
            PFU u0, u1;
            u0.i[0] = hi ? P0 : A0;  u0.i[1] = hi ? P1 : A1;
            u0.i[2] = hi ? B0 : P0;  u0.i[3] = hi ? B1 : P1;
            u1.i[0] = hi ? P2 : C0;  u1.i[1] = hi ? P3 : C1;
            u1.i[2] = hi ? D0 : P2;  u1.i[3] = hi ? D1 : P3;
            const short8 pf0 = u0.v, pf1 = u1.v;

            // ---- PV: O^T[256d x 32q] += V^T . P^T ----
            const char* vb = vbuf[pb];
            const int qh = q5 >> 3, d7 = q5 & 7;
            const int sl0 = hi * 8 + d7, sl1 = 16 + hi * 8 + d7;
            __builtin_amdgcn_s_setprio(1);   // T5
#pragma unroll
            for (int t = 0; t < 8; ++t) {
                const int dg = t * 4 + qh;
                short8 vf0 = *(const short8*)(vb + dg * 512 + ((sl0 ^ dg) << 4));
                o[t] = __builtin_amdgcn_mfma_f32_32x32x16_bf16(vf0, pf0, o[t], 0, 0, 0);
                short8 vf1 = *(const short8*)(vb + dg * 512 + ((sl1 ^ dg) << 4));
                o[t] = __builtin_amdgcn_mfma_f32_32x32x16_bf16(vf1, pf1, o[t], 0, 0, 0);
            }
            __builtin_amdgcn_s_setprio(0);
        }
        if (more) {
            char* dst = (isK ? kbuf[pb ^ 1] : vbuf[pb ^ 1]);
#pragma unroll
            for (int j = 0; j < 4; ++j)
                *(int4*)(dst + lwo[j]) = rg[j];
        }
        __syncthreads();
        pb ^= 1;
    }

    // ---- epilogue: O/l + residual; lane q=q5, d = t*32 + crow(r,hi) ----
    {
        const float inv = 1.f / li;
        const int n = w * WIN + qbw + q5;
        const float* xr  = x   + (size_t)b * DIM * NSEQ + n;
        float*       orw = out + (size_t)b * DIM * NSEQ + n;
#pragma unroll
        for (int t = 0; t < 8; ++t)
#pragma unroll
            for (int r = 0; r < 16; ++r) {
                const int d = t * 32 + (r & 3) + 8 * (r >> 2) + 4 * hi;
                orw[(size_t)d * NSEQ] = xr[(size_t)d * NSEQ] + o[t][r] * inv;
            }
    }
}

// ---------------------------------------------------------------------------
extern "C" void kernel_launch(void* const* d_in, const int* in_sizes, int n_in,
                              void* d_out, int out_size, void* d_ws, size_t ws_size,
                              hipStream_t stream) {
    const float* x  = (const float*)d_in[0];
    const float* Wq = (const float*)d_in[1];
    const float* bq = (const float*)d_in[2];
    const float* Wk = (const float*)d_in[3];
    const float* bk = (const float*)d_in[4];
    const float* Wv = (const float*)d_in[5];
    const float* bv = (const float*)d_in[6];

    char* ws = (char*)d_ws;
    const size_t SZ = (size_t)BATCH * NSEQ * DIM * sizeof(__hip_bfloat16);  // 32 MB
    __hip_bfloat16* qb_ = (__hip_bfloat16*)(ws);
    __hip_bfloat16* kb_ = (__hip_bfloat16*)(ws + SZ);
    __hip_bfloat16* vt_ = (__hip_bfloat16*)(ws + 2 * SZ);
    __hip_bfloat16* wb_ = (__hip_bfloat16*)(ws + 3 * SZ);                   // 384 KB

    k_wcast<<<dim3(192), 256, 0, stream>>>(Wq, Wk, Wv, wb_);
    k_prep<<<dim3(NSEQ / 64, BATCH), 256, 0, stream>>>(x, wb_, bq, bk, bv, qb_, kb_, vt_);
    k_attn<<<dim3(16, BATCH, 2), 512, 0, stream>>>(qb_, kb_, vt_, x, (float*)d_out);
}